// Round 1
// baseline (9068.488 us; speedup 1.0000x reference)
//
#include <hip/hip_runtime.h>
#include <math.h>

namespace {

constexpr int kB  = 8192;
constexpr int kL  = 32;
constexpr int kV  = 256;
constexpr int kH  = 512;
constexpr int kE  = 256;
constexpr int kH3 = 1536;

__device__ __forceinline__ float sigm(float x) { return 1.0f / (1.0f + expf(-x)); }

// ---------------------------------------------------------------------------
// Kernel A: G[257][1536] = [emb; sos] @ W_ih^T + b_ih   (one-time table)
// NT gemm, K=256. Row 256 is the SOS row.
// ---------------------------------------------------------------------------
__global__ __launch_bounds__(256) void g_table_kernel(
    const float* __restrict__ emb, const float* __restrict__ sos,
    const float* __restrict__ W, const float* __restrict__ bias,
    float* __restrict__ G)
{
    __shared__ __align__(16) float As[32][64];
    __shared__ __align__(16) float Bs[32][64];
    const int tid = threadIdx.x;
    const int tn = tid & 15, tm = tid >> 4;
    const int m0 = blockIdx.x * 64;
    const int n0 = blockIdx.y * 64;
    float acc[4][4] = {};
    for (int kt = 0; kt < 8; ++kt) {
        const int k0 = kt * 32;
#pragma unroll
        for (int i = 0; i < 2; ++i) {
            int l = tid + i * 256;
            int r = l >> 3, kq = l & 7;
            int row = m0 + r;
            float4 v = make_float4(0.f, 0.f, 0.f, 0.f);
            if (row < 256)       v = *(const float4*)(emb + (size_t)row * kE + k0 + kq * 4);
            else if (row == 256) v = *(const float4*)(sos + k0 + kq * 4);
            As[kq*4+0][r] = v.x; As[kq*4+1][r] = v.y; As[kq*4+2][r] = v.z; As[kq*4+3][r] = v.w;
        }
#pragma unroll
        for (int i = 0; i < 2; ++i) {
            int l = tid + i * 256;
            int r = l >> 3, kq = l & 7;
            float4 v = *(const float4*)(W + (size_t)(n0 + r) * kE + k0 + kq * 4);
            Bs[kq*4+0][r] = v.x; Bs[kq*4+1][r] = v.y; Bs[kq*4+2][r] = v.z; Bs[kq*4+3][r] = v.w;
        }
        __syncthreads();
#pragma unroll
        for (int kk = 0; kk < 32; ++kk) {
            const float4 a = *(const float4*)(&As[kk][tm*4]);
            const float4 b = *(const float4*)(&Bs[kk][tn*4]);
            const float av[4] = {a.x, a.y, a.z, a.w};
            const float bv[4] = {b.x, b.y, b.z, b.w};
#pragma unroll
            for (int i = 0; i < 4; ++i)
#pragma unroll
                for (int j = 0; j < 4; ++j)
                    acc[i][j] = fmaf(av[i], bv[j], acc[i][j]);
        }
        __syncthreads();
    }
    const int cb = n0 + tn * 4;
    const float4 bb = *(const float4*)(bias + cb);
    const float bv[4] = {bb.x, bb.y, bb.z, bb.w};
#pragma unroll
    for (int i = 0; i < 4; ++i) {
        int row = m0 + tm * 4 + i;
        if (row < 257) {
            float4 o = make_float4(acc[i][0] + bv[0], acc[i][1] + bv[1],
                                   acc[i][2] + bv[2], acc[i][3] + bv[3]);
            *(float4*)(G + (size_t)row * kH3 + cb) = o;
        }
    }
}

// ---------------------------------------------------------------------------
// Kernel B: h0[8192][512] = x @ W_i2h^T + b_i2h    NT gemm, K=256
// ---------------------------------------------------------------------------
__global__ __launch_bounds__(256) void h0_kernel(
    const float* __restrict__ x, const float* __restrict__ W,
    const float* __restrict__ bias, float* __restrict__ h0)
{
    __shared__ __align__(16) float As[32][64];
    __shared__ __align__(16) float Bs[32][64];
    const int tid = threadIdx.x;
    const int tn = tid & 15, tm = tid >> 4;
    const int m0 = blockIdx.x * 64;
    const int n0 = blockIdx.y * 64;
    float acc[4][4] = {};
    for (int kt = 0; kt < 8; ++kt) {
        const int k0 = kt * 32;
#pragma unroll
        for (int i = 0; i < 2; ++i) {
            int l = tid + i * 256;
            int r = l >> 3, kq = l & 7;
            float4 v = *(const float4*)(x + (size_t)(m0 + r) * kE + k0 + kq * 4);
            As[kq*4+0][r] = v.x; As[kq*4+1][r] = v.y; As[kq*4+2][r] = v.z; As[kq*4+3][r] = v.w;
        }
#pragma unroll
        for (int i = 0; i < 2; ++i) {
            int l = tid + i * 256;
            int r = l >> 3, kq = l & 7;
            float4 v = *(const float4*)(W + (size_t)(n0 + r) * kE + k0 + kq * 4);
            Bs[kq*4+0][r] = v.x; Bs[kq*4+1][r] = v.y; Bs[kq*4+2][r] = v.z; Bs[kq*4+3][r] = v.w;
        }
        __syncthreads();
#pragma unroll
        for (int kk = 0; kk < 32; ++kk) {
            const float4 a = *(const float4*)(&As[kk][tm*4]);
            const float4 b = *(const float4*)(&Bs[kk][tn*4]);
            const float av[4] = {a.x, a.y, a.z, a.w};
            const float bv[4] = {b.x, b.y, b.z, b.w};
#pragma unroll
            for (int i = 0; i < 4; ++i)
#pragma unroll
                for (int j = 0; j < 4; ++j)
                    acc[i][j] = fmaf(av[i], bv[j], acc[i][j]);
        }
        __syncthreads();
    }
    const int cb = n0 + tn * 4;
    const float4 bb = *(const float4*)(bias + cb);
    const float bv[4] = {bb.x, bb.y, bb.z, bb.w};
#pragma unroll
    for (int i = 0; i < 4; ++i) {
        int row = m0 + tm * 4 + i;
        float4 o = make_float4(acc[i][0] + bv[0], acc[i][1] + bv[1],
                               acc[i][2] + bv[2], acc[i][3] + bv[3]);
        *(float4*)(h0 + (size_t)row * kH + cb) = o;
    }
}

// ---------------------------------------------------------------------------
// Kernel C: one GRU step, fused gh-GEMM + gates.
// Block computes rows b0..b0+63, hidden cols j0..j0+31, all 3 gates.
// gh[b][g*512+j] = sum_k h[b][k] * W_hh[g*512+j][k]   (+ b_hh in epilogue)
// gi[.] gathered from G[tok[b]] (row 256 = SOS at t==0).
// ---------------------------------------------------------------------------
__global__ __launch_bounds__(256) void gru_step_kernel(
    const float* __restrict__ h_in, const float* __restrict__ W_hh,
    const float* __restrict__ b_hh, const float* __restrict__ G,
    const int* __restrict__ tok, const int t, float* __restrict__ h_out)
{
    __shared__ __align__(16) float As[32][64];   // [k][m]  8 KB
    __shared__ __align__(16) float Bs[32][96];   // [k][n]  12 KB
    const int tid = threadIdx.x;
    const int tn = tid & 15, tm = tid >> 4;      // tn -> 2 j's, tm -> 4 b's
    const int b0 = blockIdx.x * 64;
    const int j0 = blockIdx.y * 32;
    float acc[4][3][2] = {};                     // [m][gate][jj]
    for (int kt = 0; kt < 16; ++kt) {
        const int k0 = kt * 32;
#pragma unroll
        for (int i = 0; i < 2; ++i) {            // A: 64 rows x 32 k
            int l = tid + i * 256;
            int r = l >> 3, kq = l & 7;
            float4 v = *(const float4*)(h_in + (size_t)(b0 + r) * kH + k0 + kq * 4);
            As[kq*4+0][r] = v.x; As[kq*4+1][r] = v.y; As[kq*4+2][r] = v.z; As[kq*4+3][r] = v.w;
        }
#pragma unroll
        for (int i = 0; i < 3; ++i) {            // B: 96 W_hh rows x 32 k
            int l = tid + i * 256;
            int r = l >> 3, kq = l & 7;
            int g = r >> 5, jj = r & 31;
            float4 v = *(const float4*)(W_hh + (size_t)(g * kH + j0 + jj) * kH + k0 + kq * 4);
            Bs[kq*4+0][r] = v.x; Bs[kq*4+1][r] = v.y; Bs[kq*4+2][r] = v.z; Bs[kq*4+3][r] = v.w;
        }
        __syncthreads();
#pragma unroll
        for (int kk = 0; kk < 32; ++kk) {
            const float4 a = *(const float4*)(&As[kk][tm*4]);
            const float av[4] = {a.x, a.y, a.z, a.w};
#pragma unroll
            for (int g = 0; g < 3; ++g) {
                const float2 b = *(const float2*)(&Bs[kk][g*32 + tn*2]);
#pragma unroll
                for (int i = 0; i < 4; ++i) {
                    acc[i][g][0] = fmaf(av[i], b.x, acc[i][g][0]);
                    acc[i][g][1] = fmaf(av[i], b.y, acc[i][g][1]);
                }
            }
        }
        __syncthreads();
    }
    // epilogue: gates
    const int j = j0 + tn * 2;
    const float bhr0 = b_hh[j],        bhr1 = b_hh[j + 1];
    const float bhz0 = b_hh[512 + j],  bhz1 = b_hh[512 + j + 1];
    const float bhn0 = b_hh[1024 + j], bhn1 = b_hh[1024 + j + 1];
#pragma unroll
    for (int i = 0; i < 4; ++i) {
        const int b = b0 + tm * 4 + i;
        const int row = (t == 0) ? 256 : tok[b];
        const float* Gr = G + (size_t)row * kH3;
        float r0 = sigm(Gr[j]     + acc[i][0][0] + bhr0);
        float z0 = sigm(Gr[512+j] + acc[i][1][0] + bhz0);
        float n0 = tanhf(Gr[1024+j] + r0 * (acc[i][2][0] + bhn0));
        float r1 = sigm(Gr[j+1]     + acc[i][0][1] + bhr1);
        float z1 = sigm(Gr[512+j+1] + acc[i][1][1] + bhz1);
        float n1 = tanhf(Gr[1024+j+1] + r1 * (acc[i][2][1] + bhn1));
        const float2 hp = *(const float2*)(h_in + (size_t)b * kH + j);
        float2 o;
        o.x = (1.0f - z0) * n0 + z0 * hp.x;
        o.y = (1.0f - z1) * n1 + z1 * hp.y;
        *(float2*)(h_out + (size_t)b * kH + j) = o;
    }
}

// ---------------------------------------------------------------------------
// Kernel D: logits + argmax for step t.
// Block computes 16 batch rows x all 256 vocab cols; writes logits to d_out,
// argmax (first-max tie rule) -> tok[] (int) and token-as-float to d_out.
// ---------------------------------------------------------------------------
__global__ __launch_bounds__(256) void logit_kernel(
    const float* __restrict__ h, const float* __restrict__ W_out,
    const float* __restrict__ b_out, int* __restrict__ tok,
    float* __restrict__ out_tok, float* __restrict__ out_logits, const int t)
{
    __shared__ __align__(16) float As[32][16];    // 2 KB
    __shared__ __align__(16) float Bs[32][256];   // 32 KB
    const int tid = threadIdx.x;
    const int tn = tid & 31, tm = tid >> 5;       // tn -> 8 v's, tm -> 2 b's
    const int b0 = blockIdx.x * 16;
    float acc[2][8] = {};
    for (int kt = 0; kt < 16; ++kt) {
        const int k0 = kt * 32;
        if (tid < 128) {                          // A: 16 rows x 32 k
            int r = tid >> 3, kq = tid & 7;
            float4 v = *(const float4*)(h + (size_t)(b0 + r) * kH + k0 + kq * 4);
            As[kq*4+0][r] = v.x; As[kq*4+1][r] = v.y; As[kq*4+2][r] = v.z; As[kq*4+3][r] = v.w;
        }
#pragma unroll
        for (int i = 0; i < 8; ++i) {             // B: 256 rows x 32 k
            int l = tid + i * 256;
            int r = l >> 3, kq = l & 7;
            float4 v = *(const float4*)(W_out + (size_t)r * kH + k0 + kq * 4);
            Bs[kq*4+0][r] = v.x; Bs[kq*4+1][r] = v.y; Bs[kq*4+2][r] = v.z; Bs[kq*4+3][r] = v.w;
        }
        __syncthreads();
#pragma unroll
        for (int kk = 0; kk < 32; ++kk) {
            const float2 a = *(const float2*)(&As[kk][tm*2]);
            const float4 p = *(const float4*)(&Bs[kk][tn*8]);
            const float4 q = *(const float4*)(&Bs[kk][tn*8+4]);
            acc[0][0] = fmaf(a.x, p.x, acc[0][0]); acc[0][1] = fmaf(a.x, p.y, acc[0][1]);
            acc[0][2] = fmaf(a.x, p.z, acc[0][2]); acc[0][3] = fmaf(a.x, p.w, acc[0][3]);
            acc[0][4] = fmaf(a.x, q.x, acc[0][4]); acc[0][5] = fmaf(a.x, q.y, acc[0][5]);
            acc[0][6] = fmaf(a.x, q.z, acc[0][6]); acc[0][7] = fmaf(a.x, q.w, acc[0][7]);
            acc[1][0] = fmaf(a.y, p.x, acc[1][0]); acc[1][1] = fmaf(a.y, p.y, acc[1][1]);
            acc[1][2] = fmaf(a.y, p.z, acc[1][2]); acc[1][3] = fmaf(a.y, p.w, acc[1][3]);
            acc[1][4] = fmaf(a.y, q.x, acc[1][4]); acc[1][5] = fmaf(a.y, q.y, acc[1][5]);
            acc[1][6] = fmaf(a.y, q.z, acc[1][6]); acc[1][7] = fmaf(a.y, q.w, acc[1][7]);
        }
        __syncthreads();
    }
    const int v0 = tn * 8;
    const float4 bb0 = *(const float4*)(b_out + v0);
    const float4 bb1 = *(const float4*)(b_out + v0 + 4);
    const float bv[8] = {bb0.x, bb0.y, bb0.z, bb0.w, bb1.x, bb1.y, bb1.z, bb1.w};
#pragma unroll
    for (int i = 0; i < 2; ++i) {
        const int b = b0 + tm * 2 + i;
        float vals[8];
#pragma unroll
        for (int jv = 0; jv < 8; ++jv) vals[jv] = acc[i][jv] + bv[jv];
        float* lp = out_logits + ((size_t)b * kL + t) * kV + v0;
        *(float4*)(lp)     = make_float4(vals[0], vals[1], vals[2], vals[3]);
        *(float4*)(lp + 4) = make_float4(vals[4], vals[5], vals[6], vals[7]);
        // local argmax (ascending v -> first-max kept)
        float mx = vals[0]; int mi = v0;
#pragma unroll
        for (int jv = 1; jv < 8; ++jv)
            if (vals[jv] > mx) { mx = vals[jv]; mi = v0 + jv; }
        // reduce across the 32 lanes sharing this tm (lanes 0..31 / 32..63)
#pragma unroll
        for (int s = 16; s >= 1; s >>= 1) {
            float pm = __shfl_xor(mx, s, 64);
            int   pi = __shfl_xor(mi, s, 64);
            if (pm > mx || (pm == mx && pi < mi)) { mx = pm; mi = pi; }
        }
        if (tn == 0) {
            tok[b] = mi;
            out_tok[(size_t)b * kL + t] = (float)mi;
        }
    }
}

} // namespace

extern "C" void kernel_launch(void* const* d_in, const int* in_sizes, int n_in,
                              void* d_out, int out_size, void* d_ws, size_t ws_size,
                              hipStream_t stream) {
    const float* x      = (const float*)d_in[0];
    const float* emb    = (const float*)d_in[1];
    const float* sos    = (const float*)d_in[2];
    const float* W_i2h  = (const float*)d_in[3];
    const float* b_i2h  = (const float*)d_in[4];
    const float* W_ih   = (const float*)d_in[5];
    const float* W_hh   = (const float*)d_in[6];
    const float* b_ih   = (const float*)d_in[7];
    const float* b_hh   = (const float*)d_in[8];
    const float* W_out  = (const float*)d_in[9];
    const float* b_out  = (const float*)d_in[10];

    float* out        = (float*)d_out;           // [B*L] tokens (as float), then [B*L*V] logits
    float* out_tok    = out;
    float* out_logits = out + (size_t)kB * kL;

    float* hA  = (float*)d_ws;                   // 16 MB
    float* hB  = hA + (size_t)kB * kH;           // 16 MB
    float* G   = hB + (size_t)kB * kH;           // 257*1536*4 = 1.58 MB
    int*   tok = (int*)(G + (size_t)257 * kH3);  // 32 KB

    // one-time table + initial hidden
    g_table_kernel<<<dim3(5, 24), 256, 0, stream>>>(emb, sos, W_ih, b_ih, G);
    h0_kernel<<<dim3(kB / 64, kH / 64), 256, 0, stream>>>(x, W_i2h, b_i2h, hA);

    for (int t = 0; t < kL; ++t) {
        float* hin  = (t & 1) ? hB : hA;
        float* hout = (t & 1) ? hA : hB;
        gru_step_kernel<<<dim3(kB / 64, kH / 32), 256, 0, stream>>>(
            hin, W_hh, b_hh, G, tok, t, hout);
        logit_kernel<<<dim3(kB / 16), 256, 0, stream>>>(
            hout, W_out, b_out, tok, out_tok, out_logits, t);
    }
}

// Round 2
// 8863.509 us; speedup vs baseline: 1.0231x; 1.0231x over previous
//
#include <hip/hip_runtime.h>
#include <math.h>

namespace {

constexpr int kB  = 8192;
constexpr int kL  = 32;
constexpr int kV  = 256;
constexpr int kH  = 512;
constexpr int kE  = 256;
constexpr int kH3 = 1536;

__device__ __forceinline__ float sigm(float x) { return 1.0f / (1.0f + expf(-x)); }

__device__ __forceinline__ void gld_lds16(const float* g, float* lds) {
    __builtin_amdgcn_global_load_lds((const __attribute__((address_space(1))) void*)g,
                                     (__attribute__((address_space(3))) void*)lds, 16, 0, 0);
}

// ---------------------------------------------------------------------------
// Generic 32x32 tiled transpose: out[C][R] = in[R][C]^T  (one-time)
// ---------------------------------------------------------------------------
__global__ __launch_bounds__(256) void transpose_kernel(
    const float* __restrict__ in, float* __restrict__ out, int R, int C)
{
    __shared__ float tile[32][33];
    const int tx = threadIdx.x & 31, ty = threadIdx.x >> 5;
    const int c0 = blockIdx.x * 32, r0 = blockIdx.y * 32;
#pragma unroll
    for (int i = 0; i < 4; ++i)
        tile[ty + i * 8][tx] = in[(size_t)(r0 + ty + i * 8) * C + c0 + tx];
    __syncthreads();
#pragma unroll
    for (int i = 0; i < 4; ++i)
        out[(size_t)(c0 + ty + i * 8) * R + r0 + tx] = tile[tx][ty + i * 8];
}

// ---------------------------------------------------------------------------
// G[257][1536] = [emb; sos] @ W_ih^T + b_ih   (one-time table; row 256 = SOS)
// ---------------------------------------------------------------------------
__global__ __launch_bounds__(256) void g_table_kernel(
    const float* __restrict__ emb, const float* __restrict__ sos,
    const float* __restrict__ W, const float* __restrict__ bias,
    float* __restrict__ G)
{
    __shared__ __align__(16) float As[32][64];
    __shared__ __align__(16) float Bs[32][64];
    const int tid = threadIdx.x;
    const int tn = tid & 15, tm = tid >> 4;
    const int m0 = blockIdx.x * 64;
    const int n0 = blockIdx.y * 64;
    float acc[4][4] = {};
    for (int kt = 0; kt < 8; ++kt) {
        const int k0 = kt * 32;
#pragma unroll
        for (int i = 0; i < 2; ++i) {
            int l = tid + i * 256;
            int r = l >> 3, kq = l & 7;
            int row = m0 + r;
            float4 v = make_float4(0.f, 0.f, 0.f, 0.f);
            if (row < 256)       v = *(const float4*)(emb + (size_t)row * kE + k0 + kq * 4);
            else if (row == 256) v = *(const float4*)(sos + k0 + kq * 4);
            As[kq*4+0][r] = v.x; As[kq*4+1][r] = v.y; As[kq*4+2][r] = v.z; As[kq*4+3][r] = v.w;
        }
#pragma unroll
        for (int i = 0; i < 2; ++i) {
            int l = tid + i * 256;
            int r = l >> 3, kq = l & 7;
            float4 v = *(const float4*)(W + (size_t)(n0 + r) * kE + k0 + kq * 4);
            Bs[kq*4+0][r] = v.x; Bs[kq*4+1][r] = v.y; Bs[kq*4+2][r] = v.z; Bs[kq*4+3][r] = v.w;
        }
        __syncthreads();
#pragma unroll
        for (int kk = 0; kk < 32; ++kk) {
            const float4 a = *(const float4*)(&As[kk][tm*4]);
            const float4 b = *(const float4*)(&Bs[kk][tn*4]);
            const float av[4] = {a.x, a.y, a.z, a.w};
            const float bv[4] = {b.x, b.y, b.z, b.w};
#pragma unroll
            for (int i = 0; i < 4; ++i)
#pragma unroll
                for (int j = 0; j < 4; ++j)
                    acc[i][j] = fmaf(av[i], bv[j], acc[i][j]);
        }
        __syncthreads();
    }
    const int cb = n0 + tn * 4;
    const float4 bb = *(const float4*)(bias + cb);
    const float bv[4] = {bb.x, bb.y, bb.z, bb.w};
#pragma unroll
    for (int i = 0; i < 4; ++i) {
        int row = m0 + tm * 4 + i;
        if (row < 257) {
            float4 o = make_float4(acc[i][0] + bv[0], acc[i][1] + bv[1],
                                   acc[i][2] + bv[2], acc[i][3] + bv[3]);
            *(float4*)(G + (size_t)row * kH3 + cb) = o;
        }
    }
}

// ---------------------------------------------------------------------------
// hT[512][8192] = (x @ W_i2h^T + b_i2h)^T    (one-time, writes transposed)
// ---------------------------------------------------------------------------
__global__ __launch_bounds__(256) void h0_kernel(
    const float* __restrict__ x, const float* __restrict__ W,
    const float* __restrict__ bias, float* __restrict__ hT)
{
    __shared__ __align__(16) float As[32][64];
    __shared__ __align__(16) float Bs[32][64];
    const int tid = threadIdx.x;
    const int tn = tid & 15, tm = tid >> 4;
    const int m0 = blockIdx.x * 64;   // batch
    const int n0 = blockIdx.y * 64;   // hidden j
    float acc[4][4] = {};
    for (int kt = 0; kt < 8; ++kt) {
        const int k0 = kt * 32;
#pragma unroll
        for (int i = 0; i < 2; ++i) {
            int l = tid + i * 256;
            int r = l >> 3, kq = l & 7;
            float4 v = *(const float4*)(x + (size_t)(m0 + r) * kE + k0 + kq * 4);
            As[kq*4+0][r] = v.x; As[kq*4+1][r] = v.y; As[kq*4+2][r] = v.z; As[kq*4+3][r] = v.w;
        }
#pragma unroll
        for (int i = 0; i < 2; ++i) {
            int l = tid + i * 256;
            int r = l >> 3, kq = l & 7;
            float4 v = *(const float4*)(W + (size_t)(n0 + r) * kE + k0 + kq * 4);
            Bs[kq*4+0][r] = v.x; Bs[kq*4+1][r] = v.y; Bs[kq*4+2][r] = v.z; Bs[kq*4+3][r] = v.w;
        }
        __syncthreads();
#pragma unroll
        for (int kk = 0; kk < 32; ++kk) {
            const float4 a = *(const float4*)(&As[kk][tm*4]);
            const float4 b = *(const float4*)(&Bs[kk][tn*4]);
            const float av[4] = {a.x, a.y, a.z, a.w};
            const float bv[4] = {b.x, b.y, b.z, b.w};
#pragma unroll
            for (int i = 0; i < 4; ++i)
#pragma unroll
                for (int j = 0; j < 4; ++j)
                    acc[i][j] = fmaf(av[i], bv[j], acc[i][j]);
        }
        __syncthreads();
    }
    const int cb = n0 + tn * 4;
    const float4 bb = *(const float4*)(bias + cb);
    const float bv[4] = {bb.x, bb.y, bb.z, bb.w};
#pragma unroll
    for (int i = 0; i < 4; ++i) {
        int row = m0 + tm * 4 + i;   // batch index
#pragma unroll
        for (int c = 0; c < 4; ++c)
            hT[(size_t)(cb + c) * kB + row] = acc[i][c] + bv[c];
    }
}

// ---------------------------------------------------------------------------
// GRU step: tile 128b x (32j x 3 gates). hT layout [k][b]. W_hhT [512][1536].
// Staging via global_load_lds (linear lane->LDS mapping, conflict-free).
// Thread: 8b x 2j x 3g = 48 acc.
// ---------------------------------------------------------------------------
__global__ __launch_bounds__(256, 4) void gru_step_kernel(
    const float* __restrict__ hT_in, const float* __restrict__ W_hhT,
    const float* __restrict__ b_hh, const float* __restrict__ G,
    const int* __restrict__ tok, const int t, float* __restrict__ hT_out)
{
    __shared__ __align__(16) float As[32 * 128];   // [k][b] 16 KB
    __shared__ __align__(16) float Bs[32 * 96];    // [k][3g*32j] 12 KB
    const int tid = threadIdx.x;
    const int tn = tid & 15;        // -> j pair
    const int tm = tid >> 4;        // -> 8 b's
    const int b0 = blockIdx.x * 128;
    const int j0 = blockIdx.y * 32;

    float acc[8][3][2] = {};

    // ---- stage tile kt into LDS (async, lane-linear) ----
    auto stage = [&](int kt) {
        const int k0 = kt * 32;
#pragma unroll
        for (int i = 0; i < 4; ++i) {           // As: 32k x 128b
            int l = tid + i * 256;
            int r = l >> 5, c = l & 31;
            gld_lds16(hT_in + (size_t)(k0 + r) * kB + b0 + c * 4, &As[4 * l]);
        }
#pragma unroll
        for (int i = 0; i < 3; ++i) {           // Bs: 32k x 96n
            int l = tid + i * 256;
            int r = l / 24, q = l % 24;
            int g = q >> 3, cc = q & 7;
            gld_lds16(W_hhT + (size_t)(k0 + r) * kH3 + g * kH + j0 + cc * 4, &Bs[4 * l]);
        }
    };

    stage(0);
#pragma unroll 1
    for (int kt = 0; kt < 16; ++kt) {
        __syncthreads();                         // drains vmcnt -> tile ready
#pragma unroll 8
        for (int kk = 0; kk < 32; ++kk) {
            const float4 a0 = *(const float4*)&As[kk * 128 + tm * 8];
            const float4 a1 = *(const float4*)&As[kk * 128 + tm * 8 + 4];
            const float2 br = *(const float2*)&Bs[kk * 96 + tn * 2];
            const float2 bz = *(const float2*)&Bs[kk * 96 + 32 + tn * 2];
            const float2 bn = *(const float2*)&Bs[kk * 96 + 64 + tn * 2];
            const float av[8] = {a0.x, a0.y, a0.z, a0.w, a1.x, a1.y, a1.z, a1.w};
#pragma unroll
            for (int i = 0; i < 8; ++i) {
                acc[i][0][0] = fmaf(av[i], br.x, acc[i][0][0]);
                acc[i][0][1] = fmaf(av[i], br.y, acc[i][0][1]);
                acc[i][1][0] = fmaf(av[i], bz.x, acc[i][1][0]);
                acc[i][1][1] = fmaf(av[i], bz.y, acc[i][1][1]);
                acc[i][2][0] = fmaf(av[i], bn.x, acc[i][2][0]);
                acc[i][2][1] = fmaf(av[i], bn.y, acc[i][2][1]);
            }
        }
        __syncthreads();
        if (kt < 15) stage(kt + 1);
    }

    // ---- epilogue: gates ----
    const int j  = j0 + tn * 2;
    const int bb = b0 + tm * 8;
    const float2 bhr = *(const float2*)&b_hh[j];
    const float2 bhz = *(const float2*)&b_hh[kH + j];
    const float2 bhn = *(const float2*)&b_hh[2 * kH + j];
    const float4 hp0a = *(const float4*)&hT_in[(size_t)j * kB + bb];
    const float4 hp0b = *(const float4*)&hT_in[(size_t)j * kB + bb + 4];
    const float4 hp1a = *(const float4*)&hT_in[(size_t)(j + 1) * kB + bb];
    const float4 hp1b = *(const float4*)&hT_in[(size_t)(j + 1) * kB + bb + 4];
    const float hp[2][8] = {
        {hp0a.x, hp0a.y, hp0a.z, hp0a.w, hp0b.x, hp0b.y, hp0b.z, hp0b.w},
        {hp1a.x, hp1a.y, hp1a.z, hp1a.w, hp1b.x, hp1b.y, hp1b.z, hp1b.w}};
    int rows[8];
    if (t == 0) {
#pragma unroll
        for (int i = 0; i < 8; ++i) rows[i] = 256;
    } else {
        const int4 t0 = *(const int4*)&tok[bb];
        const int4 t1 = *(const int4*)&tok[bb + 4];
        rows[0] = t0.x; rows[1] = t0.y; rows[2] = t0.z; rows[3] = t0.w;
        rows[4] = t1.x; rows[5] = t1.y; rows[6] = t1.z; rows[7] = t1.w;
    }
    float ho[2][8];
#pragma unroll
    for (int i = 0; i < 8; ++i) {
        const float* Gr = G + (size_t)rows[i] * kH3;
        const float2 gr = *(const float2*)&Gr[j];
        const float2 gz = *(const float2*)&Gr[kH + j];
        const float2 gn = *(const float2*)&Gr[2 * kH + j];
        float r0 = sigm(gr.x + acc[i][0][0] + bhr.x);
        float z0 = sigm(gz.x + acc[i][1][0] + bhz.x);
        float n0 = tanhf(gn.x + r0 * (acc[i][2][0] + bhn.x));
        ho[0][i] = (1.0f - z0) * n0 + z0 * hp[0][i];
        float r1 = sigm(gr.y + acc[i][0][1] + bhr.y);
        float z1 = sigm(gz.y + acc[i][1][1] + bhz.y);
        float n1 = tanhf(gn.y + r1 * (acc[i][2][1] + bhn.y));
        ho[1][i] = (1.0f - z1) * n1 + z1 * hp[1][i];
    }
    *(float4*)&hT_out[(size_t)j * kB + bb]           = make_float4(ho[0][0], ho[0][1], ho[0][2], ho[0][3]);
    *(float4*)&hT_out[(size_t)j * kB + bb + 4]       = make_float4(ho[0][4], ho[0][5], ho[0][6], ho[0][7]);
    *(float4*)&hT_out[(size_t)(j + 1) * kB + bb]     = make_float4(ho[1][0], ho[1][1], ho[1][2], ho[1][3]);
    *(float4*)&hT_out[(size_t)(j + 1) * kB + bb + 4] = make_float4(ho[1][4], ho[1][5], ho[1][6], ho[1][7]);
}

// ---------------------------------------------------------------------------
// Logits + argmax for step t. Tile 32b x 256v, grid 256 (1 block/CU).
// Thread: 4b x 8v (v strided by 32 -> conflict-free scalar LDS reads).
// Register prefetch of next K-tile hides global latency.
// ---------------------------------------------------------------------------
__global__ __launch_bounds__(256) void logit_kernel(
    const float* __restrict__ hT, const float* __restrict__ W_outT,
    const float* __restrict__ b_out, int* __restrict__ tok,
    float* __restrict__ out_tok, float* __restrict__ out_logits, const int t)
{
    __shared__ __align__(16) float As[32 * 32];     // [k][b] 4 KB
    __shared__ __align__(16) float Bs[32 * 256];    // [k][v] 32 KB
    const int tid = threadIdx.x;
    const int tn = tid & 31;        // -> 8 v's (v = tn + 32m)
    const int tm = tid >> 5;        // -> 4 b's
    const int b0 = blockIdx.x * 32;
    float acc[4][8] = {};
    float4 pA;
    float4 pB[8];

    auto loadregs = [&](int kt) {
        const int k0 = kt * 32;
        {
            int r = tid >> 3, c = tid & 7;
            pA = *(const float4*)&hT[(size_t)(k0 + r) * kB + b0 + c * 4];
        }
#pragma unroll
        for (int i = 0; i < 8; ++i) {
            int l = tid + i * 256;
            int r = l >> 6, c = l & 63;
            pB[i] = *(const float4*)&W_outT[(size_t)(k0 + r) * kV + c * 4];
        }
    };

    loadregs(0);
#pragma unroll 1
    for (int kt = 0; kt < 16; ++kt) {
        *(float4*)&As[4 * tid] = pA;
#pragma unroll
        for (int i = 0; i < 8; ++i) *(float4*)&Bs[4 * (tid + i * 256)] = pB[i];
        __syncthreads();
        if (kt < 15) loadregs(kt + 1);   // in flight during compute
#pragma unroll 8
        for (int kk = 0; kk < 32; ++kk) {
            const float4 a = *(const float4*)&As[kk * 32 + tm * 4];
            const float av[4] = {a.x, a.y, a.z, a.w};
#pragma unroll
            for (int m = 0; m < 8; ++m) {
                const float bv = Bs[kk * 256 + tn + m * 32];
#pragma unroll
                for (int i = 0; i < 4; ++i)
                    acc[i][m] = fmaf(av[i], bv, acc[i][m]);
            }
        }
        __syncthreads();
    }

    float bo[8];
#pragma unroll
    for (int m = 0; m < 8; ++m) bo[m] = b_out[tn + m * 32];
#pragma unroll
    for (int i = 0; i < 4; ++i) {
        const int b = b0 + tm * 4 + i;
        float mx = -INFINITY; int mi = 0;
        float* lp = out_logits + ((size_t)b * kL + t) * kV;
#pragma unroll
        for (int m = 0; m < 8; ++m) {
            const int vi = tn + m * 32;
            const float v = acc[i][m] + bo[m];
            lp[vi] = v;
            if (v > mx) { mx = v; mi = vi; }   // vi ascending -> first-max kept
        }
#pragma unroll
        for (int s = 16; s >= 1; s >>= 1) {
            float pm = __shfl_xor(mx, s, 64);
            int   pi = __shfl_xor(mi, s, 64);
            if (pm > mx || (pm == mx && pi < mi)) { mx = pm; mi = pi; }
        }
        if (tn == 0) {
            tok[b] = mi;
            out_tok[(size_t)b * kL + t] = (float)mi;
        }
    }
}

} // namespace

extern "C" void kernel_launch(void* const* d_in, const int* in_sizes, int n_in,
                              void* d_out, int out_size, void* d_ws, size_t ws_size,
                              hipStream_t stream) {
    const float* x      = (const float*)d_in[0];
    const float* emb    = (const float*)d_in[1];
    const float* sos    = (const float*)d_in[2];
    const float* W_i2h  = (const float*)d_in[3];
    const float* b_i2h  = (const float*)d_in[4];
    const float* W_ih   = (const float*)d_in[5];
    const float* W_hh   = (const float*)d_in[6];
    const float* b_ih   = (const float*)d_in[7];
    const float* b_hh   = (const float*)d_in[8];
    const float* W_out  = (const float*)d_in[9];
    const float* b_out  = (const float*)d_in[10];

    float* out        = (float*)d_out;
    float* out_tok    = out;                         // [B*L] tokens as float
    float* out_logits = out + (size_t)kB * kL;       // [B*L*V]

    float* hA     = (float*)d_ws;                    // hT ping [512][8192]
    float* hB     = hA + (size_t)kH * kB;            // hT pong
    float* G      = hB + (size_t)kH * kB;            // [257][1536]
    float* W_hhT  = G + (size_t)257 * kH3;           // [512][1536]
    float* W_outT = W_hhT + (size_t)kH * kH3;        // [512][256]
    int*   tok    = (int*)(W_outT + (size_t)kH * kV);

    // one-time prep (independent)
    transpose_kernel<<<dim3(kH / 32, kH3 / 32), 256, 0, stream>>>(W_hh, W_hhT, kH3, kH);
    transpose_kernel<<<dim3(kH / 32, kV / 32), 256, 0, stream>>>(W_out, W_outT, kV, kH);
    g_table_kernel<<<dim3(5, kH3 / 64), 256, 0, stream>>>(emb, sos, W_ih, b_ih, G);
    h0_kernel<<<dim3(kB / 64, kH / 64), 256, 0, stream>>>(x, W_i2h, b_i2h, hA);

    for (int t = 0; t < kL; ++t) {
        float* hin  = (t & 1) ? hB : hA;
        float* hout = (t & 1) ? hA : hB;
        gru_step_kernel<<<dim3(kB / 128, kH / 32), 256, 0, stream>>>(
            hin, W_hhT, b_hh, G, tok, t, hout);
        logit_kernel<<<dim3(kB / 32), 256, 0, stream>>>(
            hout, W_outT, b_out, tok, out_tok, out_logits, t);
    }
}